// Round 9
// baseline (452.902 us; speedup 1.0000x reference)
//
#include <hip/hip_runtime.h>
#include <hip/hip_fp16.h>
#include <math.h>

// ---------------------------------------------------------------------------
// 2-layer GCN on MI355X — CSR pull aggregation (fp16) + f16 MFMA GEMM.
// Schedule (graph-capture safe):
//   cvtT W1,W2; memset cntA,cntB
//   hist_fast:  non-returning histogram -> cntA (degrees)      [~15-25us]
//   scan(cntA) -> offs; finalize -> dinv
//   FUSED [gemm1 (x@W1, dinv epilogue) || hist_rank -> rank,cntB]  2:1 block
//         interleave: MFMA waves fill returning-atomic stall bubbles
//   fill_rank: csr[offs[c]+rank[e]] = src (no atomics)
//   aggregate1 (shuffle-batched 8-deep gather) -> a1
//   gemm2 (a1@W2) ; aggregate2 -> out (f32)
// ---------------------------------------------------------------------------

typedef _Float16 f16;
typedef _Float16 f16x2 __attribute__((ext_vector_type(2)));
typedef _Float16 f16x4 __attribute__((ext_vector_type(4)));
typedef _Float16 f16x8 __attribute__((ext_vector_type(8)));
typedef float f32x4 __attribute__((ext_vector_type(4)));

#define CPAD 16  // rank-counter padding: one per 64B line

// Non-returning histogram: fire-and-forget atomics, no dependent waitcnt.
__global__ __launch_bounds__(256) void hist_fast(const int* __restrict__ ei, int E,
                                                 int* __restrict__ cnt, int N) {
  int base = (blockIdx.x * 256 + threadIdx.x) * 8;
  if (base + 8 <= E) {
    int4 c0 = *(const int4*)(ei + (size_t)E + base);
    int4 c1 = *(const int4*)(ei + (size_t)E + base + 4);
    int c[8] = {c0.x, c0.y, c0.z, c0.w, c1.x, c1.y, c1.z, c1.w};
#pragma unroll
    for (int k = 0; k < 8; ++k)
      if ((unsigned)c[k] < (unsigned)N) atomicAdd(&cnt[c[k]], 1);
  } else {
    for (int e = base; e < E; ++e) {
      int c = ei[(size_t)E + e];
      if ((unsigned)c < (unsigned)N) atomicAdd(&cnt[c], 1);
    }
  }
}

// Returning-atomic rank assignment into scratch cntB (padded).
__device__ __forceinline__ void hist_rank_body(int bid, const int* __restrict__ ei,
                                               int E, int* __restrict__ cnt,
                                               int* __restrict__ rank, int N) {
  int base = (bid * 256 + (int)threadIdx.x) * 4;
  if (base + 4 <= E) {
    int4 c4 = *(const int4*)(ei + (size_t)E + base);
    int c[4] = {c4.x, c4.y, c4.z, c4.w};
    int r[4];
#pragma unroll
    for (int k = 0; k < 4; ++k)
      r[k] = ((unsigned)c[k] < (unsigned)N) ? atomicAdd(&cnt[(size_t)c[k] * CPAD], 1)
                                            : -1;
    int4 r4 = {r[0], r[1], r[2], r[3]};
    *(int4*)(rank + base) = r4;
  } else {
    for (int e = base; e < E; ++e) {
      int c = ei[(size_t)E + e];
      rank[e] = ((unsigned)c < (unsigned)N) ? atomicAdd(&cnt[(size_t)c * CPAD], 1) : -1;
    }
  }
}

__global__ __launch_bounds__(256) void scan_partial(const int* __restrict__ cnt,
                                                    int* __restrict__ offs,
                                                    int* __restrict__ bsums,
                                                    int N) {
  __shared__ int s[256];
  int t = threadIdx.x;
  int base = blockIdx.x * 1024 + t * 4;
  int v0 = (base + 0 < N) ? cnt[base + 0] : 0;
  int v1 = (base + 1 < N) ? cnt[base + 1] : 0;
  int v2 = (base + 2 < N) ? cnt[base + 2] : 0;
  int v3 = (base + 3 < N) ? cnt[base + 3] : 0;
  int sum = v0 + v1 + v2 + v3;
  s[t] = sum;
  __syncthreads();
#pragma unroll
  for (int d = 1; d < 256; d <<= 1) {
    int x = (t >= d) ? s[t - d] : 0;
    __syncthreads();
    s[t] += x;
    __syncthreads();
  }
  int excl = s[t] - sum;
  if (base + 0 < N) offs[base + 0] = excl;
  if (base + 1 < N) offs[base + 1] = excl + v0;
  if (base + 2 < N) offs[base + 2] = excl + v0 + v1;
  if (base + 3 < N) offs[base + 3] = excl + v0 + v1 + v2;
  if (t == 255) bsums[blockIdx.x] = s[255];
}

__global__ __launch_bounds__(256) void scan_bsums(int* __restrict__ bsums, int nb) {
  __shared__ int s[256];
  int t = threadIdx.x;
  int v = (t < nb) ? bsums[t] : 0;
  s[t] = v;
  __syncthreads();
#pragma unroll
  for (int d = 1; d < 256; d <<= 1) {
    int x = (t >= d) ? s[t - d] : 0;
    __syncthreads();
    s[t] += x;
    __syncthreads();
  }
  if (t < nb) bsums[t] = s[t] - v;
}

__global__ void finalize_kernel(const int* __restrict__ cnt, int* __restrict__ offs,
                                float* __restrict__ dinv,
                                const int* __restrict__ bsums, int N, int E) {
  int i = blockIdx.x * blockDim.x + threadIdx.x;
  if (i < N) {
    offs[i] += bsums[i >> 10];
    dinv[i] = 1.0f / sqrtf((float)cnt[i] + 1.0f);
    if (i == 0) offs[N] = E;
  }
}

// No atomics: dst = offs[col] + rank. 8 edges/thread, fully pipelined.
__global__ __launch_bounds__(256) void fill_rank(const int* __restrict__ ei,
                                                 const int* __restrict__ rank,
                                                 const int* __restrict__ offs,
                                                 int E, int* __restrict__ csr, int N) {
  int base = (blockIdx.x * 256 + threadIdx.x) * 8;
  if (base + 8 <= E) {
    int4 s0 = *(const int4*)(ei + base);
    int4 s1 = *(const int4*)(ei + base + 4);
    int4 c0 = *(const int4*)(ei + (size_t)E + base);
    int4 c1 = *(const int4*)(ei + (size_t)E + base + 4);
    int4 r0 = *(const int4*)(rank + base);
    int4 r1 = *(const int4*)(rank + base + 4);
    int s[8] = {s0.x, s0.y, s0.z, s0.w, s1.x, s1.y, s1.z, s1.w};
    int c[8] = {c0.x, c0.y, c0.z, c0.w, c1.x, c1.y, c1.z, c1.w};
    int r[8] = {r0.x, r0.y, r0.z, r0.w, r1.x, r1.y, r1.z, r1.w};
#pragma unroll
    for (int k = 0; k < 8; ++k) {
      if (r[k] >= 0 && (unsigned)c[k] < (unsigned)N && (unsigned)s[k] < (unsigned)N)
        csr[offs[c[k]] + r[k]] = s[k];
    }
  } else {
    for (int e = base; e < E; ++e) {
      int s = ei[e], c = ei[(size_t)E + e], r = rank[e];
      if (r >= 0 && (unsigned)c < (unsigned)N && (unsigned)s < (unsigned)N)
        csr[offs[c] + r] = s;
    }
  }
}

// W [K][N] f32 row-major -> Wt [N][K] f16 (transposed, for B-fragment loads)
__global__ void cvtT(const float* __restrict__ W, f16* __restrict__ Wt, int K, int N) {
  int i = blockIdx.x * 256 + threadIdx.x;
  if (i < K * N) {
    int k = i / N, n = i % N;
    Wt[(size_t)n * K + k] = (f16)W[i];
  }
}

// C = A @ B, epilogue *dinv[row], out f16. A: [M,K] (f32 or f16); Bt: [NC,K] f16.
// block tile 128 x NC, BK=64; mfma_f32_16x16x32_f16. LDS rows +8 halves pad.
template <int K, int NC, bool AHALF>
__device__ __forceinline__ void gemm_body(int bid, const void* __restrict__ Ain,
                                          const f16* __restrict__ Bt,
                                          const float* __restrict__ dinv,
                                          f16* __restrict__ outp, int M,
                                          f16* alsRaw, f16* blsRaw) {
  constexpr int BM = 128, BK = 64, LDR = BK + 8;
  constexpr int NF = NC / 16;
  typedef f16(*arr_t)[LDR];
  arr_t als = (arr_t)alsRaw;
  arr_t bls = (arr_t)blsRaw;
  const int t = threadIdx.x;
  const int lane = t & 63, w = t >> 6;
  const int r0 = bid * BM;

  f32x4 acc[2][NF];
#pragma unroll
  for (int fr = 0; fr < 2; ++fr)
#pragma unroll
    for (int fc = 0; fc < NF; ++fc) acc[fr][fc] = (f32x4){0.f, 0.f, 0.f, 0.f};

  for (int kt = 0; kt < K; kt += BK) {
    if constexpr (AHALF) {
      const f16* Ag = (const f16*)Ain;
#pragma unroll
      for (int i0 = 0; i0 < 4; ++i0) {
        int i = t + i0 * 256;
        int row = i >> 3, ko = i & 7;
        int gr = min(r0 + row, M - 1);
        f16x8 v = *(const f16x8*)(Ag + (size_t)gr * K + kt + ko * 8);
        *(f16x4*)&als[row][ko * 8] = __builtin_shufflevector(v, v, 0, 1, 2, 3);
        *(f16x4*)&als[row][ko * 8 + 4] = __builtin_shufflevector(v, v, 4, 5, 6, 7);
      }
    } else {
      const float* Ag = (const float*)Ain;
#pragma unroll
      for (int i0 = 0; i0 < 8; ++i0) {
        int i = t + i0 * 256;
        int row = i >> 4, kq = i & 15;
        int gr = min(r0 + row, M - 1);
        float4 v = *(const float4*)(Ag + (size_t)gr * K + kt + kq * 4);
        f16x4 h = {(f16)v.x, (f16)v.y, (f16)v.z, (f16)v.w};
        *(f16x4*)&als[row][kq * 4] = h;
      }
    }
#pragma unroll
    for (int i0 = 0; i0 < NC / 32; ++i0) {
      int i = t + i0 * 256;
      int n = i >> 3, ko = i & 7;
      f16x8 v = *(const f16x8*)(Bt + (size_t)n * K + kt + ko * 8);
      *(f16x4*)&bls[n][ko * 8] = __builtin_shufflevector(v, v, 0, 1, 2, 3);
      *(f16x4*)&bls[n][ko * 8 + 4] = __builtin_shufflevector(v, v, 4, 5, 6, 7);
    }
    __syncthreads();
#pragma unroll
    for (int ks = 0; ks < 2; ++ks) {
      int kb = ks * 32 + ((lane >> 4) << 3);
      f16x8 a[2];
#pragma unroll
      for (int fr = 0; fr < 2; ++fr) {
        f16x4 lo = *(const f16x4*)&als[w * 32 + fr * 16 + (lane & 15)][kb];
        f16x4 hi = *(const f16x4*)&als[w * 32 + fr * 16 + (lane & 15)][kb + 4];
        a[fr] = __builtin_shufflevector(lo, hi, 0, 1, 2, 3, 4, 5, 6, 7);
      }
#pragma unroll
      for (int fc = 0; fc < NF; ++fc) {
        f16x4 lo = *(const f16x4*)&bls[fc * 16 + (lane & 15)][kb];
        f16x4 hi = *(const f16x4*)&bls[fc * 16 + (lane & 15)][kb + 4];
        f16x8 b = __builtin_shufflevector(lo, hi, 0, 1, 2, 3, 4, 5, 6, 7);
#pragma unroll
        for (int fr = 0; fr < 2; ++fr)
          acc[fr][fc] =
              __builtin_amdgcn_mfma_f32_16x16x32_f16(a[fr], b, acc[fr][fc], 0, 0, 0);
      }
    }
    __syncthreads();
  }
#pragma unroll
  for (int fr = 0; fr < 2; ++fr) {
#pragma unroll
    for (int reg = 0; reg < 4; ++reg) {
      int row = r0 + w * 32 + fr * 16 + ((lane >> 4) << 2) + reg;
      if (row < M) {
        float s = dinv[row];
#pragma unroll
        for (int fc = 0; fc < NF; ++fc)
          outp[(size_t)row * NC + fc * 16 + (lane & 15)] = (f16)(acc[fr][fc][reg] * s);
      }
    }
  }
}

template <int K, int NC, bool AHALF>
__global__ __launch_bounds__(256) void gemm_mfma(const void* __restrict__ Ain,
                                                 const f16* __restrict__ Bt,
                                                 const float* __restrict__ dinv,
                                                 f16* __restrict__ out, int M) {
  __shared__ f16 als[128 * 72];
  __shared__ f16 bls[NC * 72];
  gemm_body<K, NC, AHALF>(blockIdx.x, Ain, Bt, dinv, out, M, als, bls);
}

// Fused: gemm1 (x@W1) tiles interleaved 2:1 with hist_rank blocks so MFMA
// waves fill the returning-atomic stall bubbles on every CU.
template <int K, int NC>
__global__ __launch_bounds__(256) void fused_gemm1_hist(
    const float* __restrict__ x, const f16* __restrict__ Bt,
    const float* __restrict__ dinv, f16* __restrict__ h1, int M, int gb,
    const int* __restrict__ ei, int E, int* __restrict__ cntB,
    int* __restrict__ rank, int N, int histBlocks) {
  __shared__ f16 als[128 * 72];
  __shared__ f16 bls[NC * 72];
  int bid = blockIdx.x;
  bool isG;
  int idx;
  if (histBlocks == 2 * gb) {  // perfect 2:1 interleave (h,h,g)
    int g = bid / 3;
    if (bid % 3 == 2) {
      isG = true;
      idx = g;
    } else {
      isG = false;
      idx = bid - g;
    }
  } else {  // fallback: hist first
    if (bid < histBlocks) {
      isG = false;
      idx = bid;
    } else {
      isG = true;
      idx = bid - histBlocks;
    }
  }
  if (isG)
    gemm_body<K, NC, false>(idx, x, Bt, dinv, h1, M, als, bls);
  else
    hist_rank_body(idx, ei, E, cntB, rank, N);
}

// F=128 gather, wave per node: 64 csr indices in one coalesced read, then
// 8 independent row-gathers in flight (one waitcnt per 8).
__global__ __launch_bounds__(256) void aggregate1_f16(
    const f16* __restrict__ hs, const int* __restrict__ offs,
    const int* __restrict__ csr, const float* __restrict__ dinv,
    const float* __restrict__ bias, f16* __restrict__ out, int N) {
  int node = blockIdx.x * 4 + (threadIdx.x >> 6);
  if (node >= N) return;
  int lane = threadIdx.x & 63;
  int beg = __builtin_amdgcn_readfirstlane(offs[node]);
  int end = __builtin_amdgcn_readfirstlane(offs[node + 1]);
  float scale = dinv[node];
  f16x2 sv = *(const f16x2*)(hs + (size_t)node * 128 + lane * 2);
  float ax = (float)sv[0], ay = (float)sv[1];
  for (int j0 = beg; j0 < end; j0 += 64) {
    int cnt = min(64, end - j0);
    int myidx = 0;
    if (lane < cnt) myidx = csr[j0 + lane];
    int k = 0;
    for (; k + 8 <= cnt; k += 8) {
      f16x2 v[8];
#pragma unroll
      for (int u = 0; u < 8; ++u) {
        unsigned r = min((unsigned)__shfl(myidx, k + u), (unsigned)(N - 1));
        v[u] = *(const f16x2*)(hs + (size_t)r * 128 + lane * 2);
      }
#pragma unroll
      for (int u = 0; u < 8; ++u) {
        ax += (float)v[u][0];
        ay += (float)v[u][1];
      }
    }
    for (; k < cnt; ++k) {
      unsigned r = min((unsigned)__shfl(myidx, k), (unsigned)(N - 1));
      f16x2 v = *(const f16x2*)(hs + (size_t)r * 128 + lane * 2);
      ax += (float)v[0];
      ay += (float)v[1];
    }
  }
  float2 b = *(const float2*)(bias + lane * 2);
  float ox = fmaxf(fmaf(scale, ax, b.x), 0.f);
  float oy = fmaxf(fmaf(scale, ay, b.y), 0.f);
  f16x2 o = {(f16)ox, (f16)oy};
  *(f16x2*)(out + (size_t)node * 128 + lane * 2) = o;
}

// F=64 gather, half-wave per node; f32 output.
__global__ __launch_bounds__(256) void aggregate2_f16(
    const f16* __restrict__ hs, const int* __restrict__ offs,
    const int* __restrict__ csr, const float* __restrict__ dinv,
    const float* __restrict__ bias, float* __restrict__ out, int N) {
  int node = blockIdx.x * 8 + (threadIdx.x >> 5);
  if (node >= N) return;
  int sl = threadIdx.x & 31;
  int beg = offs[node], end = offs[node + 1];
  float scale = dinv[node];
  f16x2 sv = *(const f16x2*)(hs + (size_t)node * 64 + sl * 2);
  float ax = (float)sv[0], ay = (float)sv[1];
  for (int j0 = beg; j0 < end; j0 += 32) {
    int cnt = min(32, end - j0);
    int myidx = 0;
    if (sl < cnt) myidx = csr[j0 + sl];
    int k = 0;
    for (; k + 8 <= cnt; k += 8) {
      f16x2 v[8];
#pragma unroll
      for (int u = 0; u < 8; ++u) {
        unsigned r = min((unsigned)__shfl(myidx, k + u, 32), (unsigned)(N - 1));
        v[u] = *(const f16x2*)(hs + (size_t)r * 64 + sl * 2);
      }
#pragma unroll
      for (int u = 0; u < 8; ++u) {
        ax += (float)v[u][0];
        ay += (float)v[u][1];
      }
    }
    for (; k < cnt; ++k) {
      unsigned r = min((unsigned)__shfl(myidx, k, 32), (unsigned)(N - 1));
      f16x2 v = *(const f16x2*)(hs + (size_t)r * 64 + sl * 2);
      ax += (float)v[0];
      ay += (float)v[1];
    }
  }
  float2 b = *(const float2*)(bias + sl * 2);
  float2 o = {fmaf(scale, ax, b.x), fmaf(scale, ay, b.y)};
  *(float2*)(out + (size_t)node * 64 + sl * 2) = o;
}

extern "C" void kernel_launch(void* const* d_in, const int* in_sizes, int n_in,
                              void* d_out, int out_size, void* d_ws, size_t ws_size,
                              hipStream_t stream) {
  const float* x = (const float*)d_in[0];
  const int* ei = (const int*)d_in[1];
  const float* W1 = (const float*)d_in[2];
  const float* b1 = (const float*)d_in[3];
  const float* W2 = (const float*)d_in[4];
  const float* b2 = (const float*)d_in[5];
  float* out = (float*)d_out;

  const int IN = 256, HID = 128, OUT = 64;
  int N = in_sizes[0] / IN;   // 100000
  int E = in_sizes[1] / 2;    // 1600000

  char* ws = (char*)d_ws;
  size_t off = 0;
  auto alloc = [&](size_t bytes) -> void* {
    void* p = ws + off;
    off += (bytes + 255) & ~(size_t)255;
    return p;
  };
  int* cntA = (int*)alloc((size_t)N * 4);            // degrees (non-returning)
  int* cntB = (int*)alloc((size_t)N * CPAD * 4);     // rank counters (padded)
  int* offs = (int*)alloc(((size_t)N + 1) * 4);
  int* rank = (int*)alloc((size_t)E * 4);
  float* dinv = (float*)alloc((size_t)N * 4);
  int* bsums = (int*)alloc(1024 * 4);
  int* csr = (int*)alloc((size_t)E * 4);
  f16* Wt1 = (f16*)alloc((size_t)IN * HID * 2);
  f16* Wt2 = (f16*)alloc((size_t)HID * OUT * 2);
  f16* h1s = (f16*)alloc((size_t)N * HID * 2);
  f16* a1 = (f16*)alloc((size_t)N * HID * 2);
  f16* h2s = h1s;  // dead after aggregate1; reuse

  cvtT<<<(IN * HID + 255) / 256, 256, 0, stream>>>(W1, Wt1, IN, HID);
  cvtT<<<(HID * OUT + 255) / 256, 256, 0, stream>>>(W2, Wt2, HID, OUT);

  hipMemsetAsync(cntA, 0, (size_t)N * 4, stream);
  hipMemsetAsync(cntB, 0, (size_t)N * CPAD * 4, stream);

  int eb8 = (E / 8 + 255) / 256 + 1;
  hist_fast<<<eb8, 256, 0, stream>>>(ei, E, cntA, N);
  int nb = (N + 1023) / 1024;
  scan_partial<<<nb, 256, 0, stream>>>(cntA, offs, bsums, N);
  scan_bsums<<<1, 256, 0, stream>>>(bsums, nb);
  finalize_kernel<<<(N + 255) / 256, 256, 0, stream>>>(cntA, offs, dinv, bsums, N, E);

  int gb = (N + 127) / 128;
  int eb4 = (E / 4 + 255) / 256 + 1;
  fused_gemm1_hist<256, 128><<<gb + eb4, 256, 0, stream>>>(
      x, Wt1, dinv, h1s, N, gb, ei, E, cntB, rank, N, eb4);

  fill_rank<<<eb8, 256, 0, stream>>>(ei, rank, offs, E, csr, N);
  aggregate1_f16<<<(N + 3) / 4, 256, 0, stream>>>(h1s, offs, csr, dinv, b1, a1, N);
  gemm_mfma<128, 64, true><<<gb, 256, 0, stream>>>(a1, Wt2, dinv, h2s, N);
  aggregate2_f16<<<(N + 7) / 8, 256, 0, stream>>>(h2s, offs, csr, dinv, b2, out, N);
}

// Round 10
// 389.209 us; speedup vs baseline: 1.1636x; 1.1636x over previous
//
#include <hip/hip_runtime.h>
#include <hip/hip_fp16.h>
#include <math.h>

// ---------------------------------------------------------------------------
// 2-layer GCN on MI355X — CSR pull aggregation (fp16) + f16 MFMA GEMM.
// Schedule (graph-capture safe):
//   cvtT W1,W2; memset cntB
//   FUSED: [hist_rank: 256 grid-stride blocks dispatched FIRST (1/CU resident,
//           saturate atomic queue) || gemm1 x@W1 RAW (no dinv) 782 tiles]
//   scan(cntB padded) -> offs; finalize -> dinv  (degrees = final counters)
//   fill_rank: csr[offs[c]+rank[e]] = src (no atomics)
//   aggregate1: relu(dinv[c]*(sum dinv[r]*h1[r]) + b1)  [per-edge dinv bcast]
//   gemm2 (a1@W2, dinv epilogue); aggregate2 -> out (f32)
// ---------------------------------------------------------------------------

typedef _Float16 f16;
typedef _Float16 f16x2 __attribute__((ext_vector_type(2)));
typedef _Float16 f16x4 __attribute__((ext_vector_type(4)));
typedef _Float16 f16x8 __attribute__((ext_vector_type(8)));
typedef float f32x4 __attribute__((ext_vector_type(4)));

#define CPAD 16  // rank-counter padding: one per 64B line

// Grid-stride returning-atomic rank assignment (also produces degrees).
// histBlocks blocks total; each thread 4 atomics in flight per batch.
__device__ __forceinline__ void hist_rank_body(int hb, int histBlocks,
                                               const int* __restrict__ ei, int E,
                                               int* __restrict__ cnt,
                                               int* __restrict__ rank, int N) {
  int stride = histBlocks * 256 * 4;
  for (int base = (hb * 256 + (int)threadIdx.x) * 4; base < E; base += stride) {
    if (base + 4 <= E) {
      int4 c4 = *(const int4*)(ei + (size_t)E + base);
      int c[4] = {c4.x, c4.y, c4.z, c4.w};
      int r[4];
#pragma unroll
      for (int k = 0; k < 4; ++k)
        r[k] = ((unsigned)c[k] < (unsigned)N)
                   ? atomicAdd(&cnt[(size_t)c[k] * CPAD], 1)
                   : -1;
      int4 r4 = {r[0], r[1], r[2], r[3]};
      *(int4*)(rank + base) = r4;
    } else {
      for (int e = base; e < E; ++e) {
        int c = ei[(size_t)E + e];
        rank[e] =
            ((unsigned)c < (unsigned)N) ? atomicAdd(&cnt[(size_t)c * CPAD], 1) : -1;
      }
    }
  }
}

__global__ __launch_bounds__(256) void scan_partial(const int* __restrict__ cnt,
                                                    int* __restrict__ offs,
                                                    int* __restrict__ bsums,
                                                    int N) {
  __shared__ int s[256];
  int t = threadIdx.x;
  int base = blockIdx.x * 1024 + t * 4;
  int v0 = (base + 0 < N) ? cnt[(size_t)(base + 0) * CPAD] : 0;
  int v1 = (base + 1 < N) ? cnt[(size_t)(base + 1) * CPAD] : 0;
  int v2 = (base + 2 < N) ? cnt[(size_t)(base + 2) * CPAD] : 0;
  int v3 = (base + 3 < N) ? cnt[(size_t)(base + 3) * CPAD] : 0;
  int sum = v0 + v1 + v2 + v3;
  s[t] = sum;
  __syncthreads();
#pragma unroll
  for (int d = 1; d < 256; d <<= 1) {
    int x = (t >= d) ? s[t - d] : 0;
    __syncthreads();
    s[t] += x;
    __syncthreads();
  }
  int excl = s[t] - sum;
  if (base + 0 < N) offs[base + 0] = excl;
  if (base + 1 < N) offs[base + 1] = excl + v0;
  if (base + 2 < N) offs[base + 2] = excl + v0 + v1;
  if (base + 3 < N) offs[base + 3] = excl + v0 + v1 + v2;
  if (t == 255) bsums[blockIdx.x] = s[255];
}

__global__ __launch_bounds__(256) void scan_bsums(int* __restrict__ bsums, int nb) {
  __shared__ int s[256];
  int t = threadIdx.x;
  int v = (t < nb) ? bsums[t] : 0;
  s[t] = v;
  __syncthreads();
#pragma unroll
  for (int d = 1; d < 256; d <<= 1) {
    int x = (t >= d) ? s[t - d] : 0;
    __syncthreads();
    s[t] += x;
    __syncthreads();
  }
  if (t < nb) bsums[t] = s[t] - v;
}

__global__ void finalize_kernel(const int* __restrict__ cnt, int* __restrict__ offs,
                                float* __restrict__ dinv,
                                const int* __restrict__ bsums, int N, int E) {
  int i = blockIdx.x * blockDim.x + threadIdx.x;
  if (i < N) {
    offs[i] += bsums[i >> 10];
    dinv[i] = 1.0f / sqrtf((float)cnt[(size_t)i * CPAD] + 1.0f);
    if (i == 0) offs[N] = E;
  }
}

// No atomics: dst = offs[col] + rank. 8 edges/thread, fully pipelined.
__global__ __launch_bounds__(256) void fill_rank(const int* __restrict__ ei,
                                                 const int* __restrict__ rank,
                                                 const int* __restrict__ offs,
                                                 int E, int* __restrict__ csr, int N) {
  int base = (blockIdx.x * 256 + threadIdx.x) * 8;
  if (base + 8 <= E) {
    int4 s0 = *(const int4*)(ei + base);
    int4 s1 = *(const int4*)(ei + base + 4);
    int4 c0 = *(const int4*)(ei + (size_t)E + base);
    int4 c1 = *(const int4*)(ei + (size_t)E + base + 4);
    int4 r0 = *(const int4*)(rank + base);
    int4 r1 = *(const int4*)(rank + base + 4);
    int s[8] = {s0.x, s0.y, s0.z, s0.w, s1.x, s1.y, s1.z, s1.w};
    int c[8] = {c0.x, c0.y, c0.z, c0.w, c1.x, c1.y, c1.z, c1.w};
    int r[8] = {r0.x, r0.y, r0.z, r0.w, r1.x, r1.y, r1.z, r1.w};
#pragma unroll
    for (int k = 0; k < 8; ++k) {
      if (r[k] >= 0 && (unsigned)c[k] < (unsigned)N && (unsigned)s[k] < (unsigned)N)
        csr[offs[c[k]] + r[k]] = s[k];
    }
  } else {
    for (int e = base; e < E; ++e) {
      int s = ei[e], c = ei[(size_t)E + e], r = rank[e];
      if (r >= 0 && (unsigned)c < (unsigned)N && (unsigned)s < (unsigned)N)
        csr[offs[c] + r] = s;
    }
  }
}

// W [K][N] f32 row-major -> Wt [N][K] f16 (transposed, for B-fragment loads)
__global__ void cvtT(const float* __restrict__ W, f16* __restrict__ Wt, int K, int N) {
  int i = blockIdx.x * 256 + threadIdx.x;
  if (i < K * N) {
    int k = i / N, n = i % N;
    Wt[(size_t)n * K + k] = (f16)W[i];
  }
}

// C = A @ B, optional epilogue *dinv[row] (dinv may be null), out f16.
// block tile 128 x NC, BK=64; mfma_f32_16x16x32_f16. LDS rows +8 halves pad.
template <int K, int NC, bool AHALF>
__device__ __forceinline__ void gemm_body(int bid, const void* __restrict__ Ain,
                                          const f16* __restrict__ Bt,
                                          const float* __restrict__ dinv,
                                          f16* __restrict__ outp, int M,
                                          f16* alsRaw, f16* blsRaw) {
  constexpr int BM = 128, BK = 64, LDR = BK + 8;
  constexpr int NF = NC / 16;
  typedef f16(*arr_t)[LDR];
  arr_t als = (arr_t)alsRaw;
  arr_t bls = (arr_t)blsRaw;
  const int t = threadIdx.x;
  const int lane = t & 63, w = t >> 6;
  const int r0 = bid * BM;

  f32x4 acc[2][NF];
#pragma unroll
  for (int fr = 0; fr < 2; ++fr)
#pragma unroll
    for (int fc = 0; fc < NF; ++fc) acc[fr][fc] = (f32x4){0.f, 0.f, 0.f, 0.f};

  for (int kt = 0; kt < K; kt += BK) {
    if constexpr (AHALF) {
      const f16* Ag = (const f16*)Ain;
#pragma unroll
      for (int i0 = 0; i0 < 4; ++i0) {
        int i = t + i0 * 256;
        int row = i >> 3, ko = i & 7;
        int gr = min(r0 + row, M - 1);
        f16x8 v = *(const f16x8*)(Ag + (size_t)gr * K + kt + ko * 8);
        *(f16x4*)&als[row][ko * 8] = __builtin_shufflevector(v, v, 0, 1, 2, 3);
        *(f16x4*)&als[row][ko * 8 + 4] = __builtin_shufflevector(v, v, 4, 5, 6, 7);
      }
    } else {
      const float* Ag = (const float*)Ain;
#pragma unroll
      for (int i0 = 0; i0 < 8; ++i0) {
        int i = t + i0 * 256;
        int row = i >> 4, kq = i & 15;
        int gr = min(r0 + row, M - 1);
        float4 v = *(const float4*)(Ag + (size_t)gr * K + kt + kq * 4);
        f16x4 h = {(f16)v.x, (f16)v.y, (f16)v.z, (f16)v.w};
        *(f16x4*)&als[row][kq * 4] = h;
      }
    }
#pragma unroll
    for (int i0 = 0; i0 < NC / 32; ++i0) {
      int i = t + i0 * 256;
      int n = i >> 3, ko = i & 7;
      f16x8 v = *(const f16x8*)(Bt + (size_t)n * K + kt + ko * 8);
      *(f16x4*)&bls[n][ko * 8] = __builtin_shufflevector(v, v, 0, 1, 2, 3);
      *(f16x4*)&bls[n][ko * 8 + 4] = __builtin_shufflevector(v, v, 4, 5, 6, 7);
    }
    __syncthreads();
#pragma unroll
    for (int ks = 0; ks < 2; ++ks) {
      int kb = ks * 32 + ((lane >> 4) << 3);
      f16x8 a[2];
#pragma unroll
      for (int fr = 0; fr < 2; ++fr) {
        f16x4 lo = *(const f16x4*)&als[w * 32 + fr * 16 + (lane & 15)][kb];
        f16x4 hi = *(const f16x4*)&als[w * 32 + fr * 16 + (lane & 15)][kb + 4];
        a[fr] = __builtin_shufflevector(lo, hi, 0, 1, 2, 3, 4, 5, 6, 7);
      }
#pragma unroll
      for (int fc = 0; fc < NF; ++fc) {
        f16x4 lo = *(const f16x4*)&bls[fc * 16 + (lane & 15)][kb];
        f16x4 hi = *(const f16x4*)&bls[fc * 16 + (lane & 15)][kb + 4];
        f16x8 b = __builtin_shufflevector(lo, hi, 0, 1, 2, 3, 4, 5, 6, 7);
#pragma unroll
        for (int fr = 0; fr < 2; ++fr)
          acc[fr][fc] =
              __builtin_amdgcn_mfma_f32_16x16x32_f16(a[fr], b, acc[fr][fc], 0, 0, 0);
      }
    }
    __syncthreads();
  }
#pragma unroll
  for (int fr = 0; fr < 2; ++fr) {
#pragma unroll
    for (int reg = 0; reg < 4; ++reg) {
      int row = r0 + w * 32 + fr * 16 + ((lane >> 4) << 2) + reg;
      if (row < M) {
        float s = dinv ? dinv[row] : 1.0f;
#pragma unroll
        for (int fc = 0; fc < NF; ++fc)
          outp[(size_t)row * NC + fc * 16 + (lane & 15)] = (f16)(acc[fr][fc][reg] * s);
      }
    }
  }
}

template <int K, int NC, bool AHALF>
__global__ __launch_bounds__(256) void gemm_mfma(const void* __restrict__ Ain,
                                                 const f16* __restrict__ Bt,
                                                 const float* __restrict__ dinv,
                                                 f16* __restrict__ out, int M) {
  __shared__ f16 als[128 * 72];
  __shared__ f16 bls[NC * 72];
  gemm_body<K, NC, AHALF>(blockIdx.x, Ain, Bt, dinv, out, M, als, bls);
}

// Fused: first histBlocks blocks are long-lived grid-stride hist residents
// (~1/CU, saturating the device atomic queue); remaining blocks are gemm1
// tiles that fill the other block slots with MFMA work.
template <int K, int NC>
__global__ __launch_bounds__(256) void fused_gemm1_hist(
    const float* __restrict__ x, const f16* __restrict__ Bt, f16* __restrict__ h1,
    int M, const int* __restrict__ ei, int E, int* __restrict__ cntB,
    int* __restrict__ rank, int N, int histBlocks) {
  __shared__ f16 als[128 * 72];
  __shared__ f16 bls[NC * 72];
  int bid = blockIdx.x;
  if (bid < histBlocks) {
    hist_rank_body(bid, histBlocks, ei, E, cntB, rank, N);
  } else {
    gemm_body<K, NC, false>(bid - histBlocks, x, Bt, nullptr, h1, M, als, bls);
  }
}

// F=128 gather, wave per node. h1 is UNSCALED: apply dinv[src] per gathered
// row (wave-uniform 4B broadcast from 400KB L2-resident table).
__global__ __launch_bounds__(256) void aggregate1_f16(
    const f16* __restrict__ hs, const int* __restrict__ offs,
    const int* __restrict__ csr, const float* __restrict__ dinv,
    const float* __restrict__ bias, f16* __restrict__ out, int N) {
  int node = blockIdx.x * 4 + (threadIdx.x >> 6);
  if (node >= N) return;
  int lane = threadIdx.x & 63;
  int beg = __builtin_amdgcn_readfirstlane(offs[node]);
  int end = __builtin_amdgcn_readfirstlane(offs[node + 1]);
  float scale = dinv[node];
  f16x2 sv = *(const f16x2*)(hs + (size_t)node * 128 + lane * 2);
  float ax = scale * (float)sv[0], ay = scale * (float)sv[1];  // self * dinv[node]
  for (int j0 = beg; j0 < end; j0 += 64) {
    int cnt = min(64, end - j0);
    int myidx = 0;
    if (lane < cnt) myidx = csr[j0 + lane];
    int k = 0;
    for (; k + 8 <= cnt; k += 8) {
      f16x2 v[8];
      float d[8];
#pragma unroll
      for (int u = 0; u < 8; ++u) {
        unsigned r = min((unsigned)__shfl(myidx, k + u), (unsigned)(N - 1));
        v[u] = *(const f16x2*)(hs + (size_t)r * 128 + lane * 2);
        d[u] = dinv[r];
      }
#pragma unroll
      for (int u = 0; u < 8; ++u) {
        ax = fmaf(d[u], (float)v[u][0], ax);
        ay = fmaf(d[u], (float)v[u][1], ay);
      }
    }
    for (; k < cnt; ++k) {
      unsigned r = min((unsigned)__shfl(myidx, k), (unsigned)(N - 1));
      f16x2 v = *(const f16x2*)(hs + (size_t)r * 128 + lane * 2);
      float d = dinv[r];
      ax = fmaf(d, (float)v[0], ax);
      ay = fmaf(d, (float)v[1], ay);
    }
  }
  float2 b = *(const float2*)(bias + lane * 2);
  float ox = fmaxf(fmaf(scale, ax, b.x), 0.f);
  float oy = fmaxf(fmaf(scale, ay, b.y), 0.f);
  f16x2 o = {(f16)ox, (f16)oy};
  *(f16x2*)(out + (size_t)node * 128 + lane * 2) = o;
}

// F=64 gather, half-wave per node; h2s pre-scaled (gemm2 epilogue); f32 out.
__global__ __launch_bounds__(256) void aggregate2_f16(
    const f16* __restrict__ hs, const int* __restrict__ offs,
    const int* __restrict__ csr, const float* __restrict__ dinv,
    const float* __restrict__ bias, float* __restrict__ out, int N) {
  int node = blockIdx.x * 8 + (threadIdx.x >> 5);
  if (node >= N) return;
  int sl = threadIdx.x & 31;
  int beg = offs[node], end = offs[node + 1];
  float scale = dinv[node];
  f16x2 sv = *(const f16x2*)(hs + (size_t)node * 64 + sl * 2);
  float ax = (float)sv[0], ay = (float)sv[1];
  for (int j0 = beg; j0 < end; j0 += 32) {
    int cnt = min(32, end - j0);
    int myidx = 0;
    if (sl < cnt) myidx = csr[j0 + sl];
    int k = 0;
    for (; k + 8 <= cnt; k += 8) {
      f16x2 v[8];
#pragma unroll
      for (int u = 0; u < 8; ++u) {
        unsigned r = min((unsigned)__shfl(myidx, k + u, 32), (unsigned)(N - 1));
        v[u] = *(const f16x2*)(hs + (size_t)r * 64 + sl * 2);
      }
#pragma unroll
      for (int u = 0; u < 8; ++u) {
        ax += (float)v[u][0];
        ay += (float)v[u][1];
      }
    }
    for (; k < cnt; ++k) {
      unsigned r = min((unsigned)__shfl(myidx, k, 32), (unsigned)(N - 1));
      f16x2 v = *(const f16x2*)(hs + (size_t)r * 64 + sl * 2);
      ax += (float)v[0];
      ay += (float)v[1];
    }
  }
  float2 b = *(const float2*)(bias + sl * 2);
  float2 o = {fmaf(scale, ax, b.x), fmaf(scale, ay, b.y)};
  *(float2*)(out + (size_t)node * 64 + sl * 2) = o;
}

extern "C" void kernel_launch(void* const* d_in, const int* in_sizes, int n_in,
                              void* d_out, int out_size, void* d_ws, size_t ws_size,
                              hipStream_t stream) {
  const float* x = (const float*)d_in[0];
  const int* ei = (const int*)d_in[1];
  const float* W1 = (const float*)d_in[2];
  const float* b1 = (const float*)d_in[3];
  const float* W2 = (const float*)d_in[4];
  const float* b2 = (const float*)d_in[5];
  float* out = (float*)d_out;

  const int IN = 256, HID = 128, OUT = 64;
  int N = in_sizes[0] / IN;   // 100000
  int E = in_sizes[1] / 2;    // 1600000

  char* ws = (char*)d_ws;
  size_t off = 0;
  auto alloc = [&](size_t bytes) -> void* {
    void* p = ws + off;
    off += (bytes + 255) & ~(size_t)255;
    return p;
  };
  int* cntB = (int*)alloc((size_t)N * CPAD * 4);  // rank counters -> degrees
  int* offs = (int*)alloc(((size_t)N + 1) * 4);
  int* rank = (int*)alloc((size_t)E * 4);
  float* dinv = (float*)alloc((size_t)N * 4);
  int* bsums = (int*)alloc(1024 * 4);
  int* csr = (int*)alloc((size_t)E * 4);
  f16* Wt1 = (f16*)alloc((size_t)IN * HID * 2);
  f16* Wt2 = (f16*)alloc((size_t)HID * OUT * 2);
  f16* h1s = (f16*)alloc((size_t)N * HID * 2);
  f16* a1 = (f16*)alloc((size_t)N * HID * 2);
  f16* h2s = h1s;  // dead after aggregate1; reuse

  cvtT<<<(IN * HID + 255) / 256, 256, 0, stream>>>(W1, Wt1, IN, HID);
  cvtT<<<(HID * OUT + 255) / 256, 256, 0, stream>>>(W2, Wt2, HID, OUT);
  hipMemsetAsync(cntB, 0, (size_t)N * CPAD * 4, stream);

  int gb = (N + 127) / 128;          // 782 gemm tiles
  const int histBlocks = 256;        // one resident hist block per CU
  fused_gemm1_hist<256, 128><<<histBlocks + gb, 256, 0, stream>>>(
      x, Wt1, h1s, N, ei, E, cntB, rank, N, histBlocks);

  int nb = (N + 1023) / 1024;
  scan_partial<<<nb, 256, 0, stream>>>(cntB, offs, bsums, N);
  scan_bsums<<<1, 256, 0, stream>>>(bsums, nb);
  finalize_kernel<<<(N + 255) / 256, 256, 0, stream>>>(cntB, offs, dinv, bsums, N, E);

  int eb8 = (E / 8 + 255) / 256 + 1;
  fill_rank<<<eb8, 256, 0, stream>>>(ei, rank, offs, E, csr, N);
  aggregate1_f16<<<(N + 3) / 4, 256, 0, stream>>>(h1s, offs, csr, dinv, b1, a1, N);
  gemm_mfma<128, 64, true><<<gb, 256, 0, stream>>>(a1, Wt2, dinv, h2s, N);
  aggregate2_f16<<<(N + 7) / 8, 256, 0, stream>>>(h2s, offs, csr, dinv, b2, out, N);
}

// Round 11
// 381.445 us; speedup vs baseline: 1.1873x; 1.0204x over previous
//
#include <hip/hip_runtime.h>
#include <hip/hip_fp16.h>
#include <math.h>

// ---------------------------------------------------------------------------
// 2-layer GCN on MI355X — bucketed CSR build (LDS atomics only) + f16 MFMA.
// edge_index arrives as int32 [2][E] flat: first E = sources, next E = targets.
// Build (NO global returning atomics — those hit a ~42ns/op memory-side floor):
//   pass1: 1024 blocks LDS-histogram their edge chunk by bucket(col>>9)
//          -> cntmat[block][bucket]  (coalesced writes, no global atomics)
//   scan_cntmat: per-bucket exclusive scan over blocks -> basemat; scan_bsums
//   pass2: re-read chunk, LDS returning-atomic cursors -> scatter (src,col)
//          into bucket-contiguous bucket_arr
//   pass3: one block per bucket: LDS count -> in-block scan -> offs+dinv
//          written directly (bucket-local prefix + segment base), then
//          LDS-cursor fill: csr[pos]=src (bucket csr region is contiguous)
// Compute:
//   h1s = f16(x @ W1)  [raw]          aggregate1: relu(dinv[c]*Σ dinv[r]*h1[r]+b1)
//   h2s = f16(dinv .* (a1 @ W2))      aggregate2: dinv[c]*Σ h2s + b2 -> f32 out
// ---------------------------------------------------------------------------

typedef _Float16 f16;
typedef _Float16 f16x2 __attribute__((ext_vector_type(2)));
typedef _Float16 f16x4 __attribute__((ext_vector_type(4)));
typedef _Float16 f16x8 __attribute__((ext_vector_type(8)));
typedef float f32x4 __attribute__((ext_vector_type(4)));

#define NBLK1 1024   // blocks in pass1/pass2
#define NPB 512      // nodes per bucket (bucket = col >> 9)
#define NBMAX 256    // max buckets supported (N <= 131072)

// pass1: per-(block,bucket) histogram via LDS, no global atomics.
__global__ __launch_bounds__(256) void pass1_count(const int* __restrict__ ei, int E,
                                                   int* __restrict__ cntmat, int N,
                                                   int NB, int EPB) {
  __shared__ int bcnt[NBMAX];
  int t = threadIdx.x;
  for (int j = t; j < NB; j += 256) bcnt[j] = 0;
  __syncthreads();
  int beg = blockIdx.x * EPB, end = min(E, beg + EPB);
  for (int e = beg + t; e < end; e += 256) {
    int c = ei[(size_t)E + e];
    if ((unsigned)c < (unsigned)N) atomicAdd(&bcnt[c >> 9], 1);
  }
  __syncthreads();
  for (int j = t; j < NB; j += 256) cntmat[(size_t)blockIdx.x * NB + j] = bcnt[j];
}

// One block per bucket g: exclusive scan of cntmat[0..1023][g] (1024 vals,
// 4/thread), basemat[g*1024+blk] = local excl, bsums2[g] = total.
__global__ __launch_bounds__(256) void scan_cntmat(const int* __restrict__ cntmat,
                                                   int* __restrict__ basemat,
                                                   int* __restrict__ bsums2, int NB) {
  __shared__ int s[256];
  int t = threadIdx.x, g = blockIdx.x;
  int v[4];
#pragma unroll
  for (int u = 0; u < 4; ++u) v[u] = cntmat[(size_t)(t * 4 + u) * NB + g];
  int sum = v[0] + v[1] + v[2] + v[3];
  s[t] = sum;
  __syncthreads();
#pragma unroll
  for (int d = 1; d < 256; d <<= 1) {
    int x = (t >= d) ? s[t - d] : 0;
    __syncthreads();
    s[t] += x;
    __syncthreads();
  }
  int excl = s[t] - sum;
  int o = excl;
  int* bm = basemat + (size_t)g * NBLK1 + t * 4;
#pragma unroll
  for (int u = 0; u < 4; ++u) {
    bm[u] = o;
    o += v[u];
  }
  if (t == 255) bsums2[g] = s[255];
}

__global__ __launch_bounds__(256) void scan_bsums(int* __restrict__ bsums, int nb) {
  __shared__ int s[256];
  int t = threadIdx.x;
  int v = (t < nb) ? bsums[t] : 0;
  s[t] = v;
  __syncthreads();
#pragma unroll
  for (int d = 1; d < 256; d <<= 1) {
    int x = (t >= d) ? s[t - d] : 0;
    __syncthreads();
    s[t] += x;
    __syncthreads();
  }
  if (t < nb) bsums[t] = s[t] - v;
}

// pass2: scatter (src,col) to bucket-contiguous bucket_arr. Cursors in LDS
// (fast ds_add_rtn), pre-reserved per (block,bucket) -> race-free.
__global__ __launch_bounds__(256) void pass2_scatter(const int* __restrict__ ei, int E,
                                                     const int* __restrict__ basemat,
                                                     const int* __restrict__ bsums2,
                                                     int2* __restrict__ bucket_arr,
                                                     int N, int NB, int EPB) {
  __shared__ int curs[NBMAX];
  int t = threadIdx.x, bid = blockIdx.x;
  for (int j = t; j < NB; j += 256)
    curs[j] = basemat[(size_t)j * NBLK1 + bid] + bsums2[j];
  __syncthreads();
  int beg = bid * EPB, end = min(E, beg + EPB);
  for (int e = beg + t; e < end; e += 256) {
    int c = ei[(size_t)E + e];
    if ((unsigned)c < (unsigned)N) {
      int srcv = ei[e];
      int pos = atomicAdd(&curs[c >> 9], 1);
      bucket_arr[pos] = make_int2(srcv, c);
    }
  }
}

// pass3: per-bucket count -> in-block scan -> offs/dinv -> LDS-cursor fill.
__global__ __launch_bounds__(256) void pass3_build(const int2* __restrict__ bucket_arr,
                                                   const int* __restrict__ basemat,
                                                   const int* __restrict__ bsums2,
                                                   int* __restrict__ offs,
                                                   float* __restrict__ dinv,
                                                   int* __restrict__ csr, int E, int N,
                                                   int NB) {
  __shared__ int cnt[NPB];
  __shared__ int curs[NPB];
  __shared__ int s[256];
  int t = threadIdx.x, b = blockIdx.x;
  int lo = b * NPB;
  cnt[t] = 0;
  cnt[t + 256] = 0;
  __syncthreads();
  int beg = basemat[(size_t)b * NBLK1] + bsums2[b];
  int end = (b + 1 < NB) ? (basemat[(size_t)(b + 1) * NBLK1] + bsums2[b + 1]) : E;
  for (int e = beg + t; e < end; e += 256) {
    int2 sc = bucket_arr[e];
    unsigned idx = (unsigned)(sc.y - lo);
    if (idx < NPB) atomicAdd(&cnt[idx], 1);
  }
  __syncthreads();
  // exclusive scan of cnt[512]: 2 vals/thread
  int v0 = cnt[2 * t], v1 = cnt[2 * t + 1];
  int sum = v0 + v1;
  s[t] = sum;
  __syncthreads();
#pragma unroll
  for (int d = 1; d < 256; d <<= 1) {
    int x = (t >= d) ? s[t - d] : 0;
    __syncthreads();
    s[t] += x;
    __syncthreads();
  }
  int excl = s[t] - sum;
  int o0 = beg + excl, o1 = beg + excl + v0;
  curs[2 * t] = o0;
  curs[2 * t + 1] = o1;
  if (lo + 2 * t < N) {
    offs[lo + 2 * t] = o0;
    dinv[lo + 2 * t] = 1.0f / sqrtf((float)v0 + 1.0f);
  }
  if (lo + 2 * t + 1 < N) {
    offs[lo + 2 * t + 1] = o1;
    dinv[lo + 2 * t + 1] = 1.0f / sqrtf((float)v1 + 1.0f);
  }
  if (b == NB - 1 && t == 0) offs[N] = E;
  __syncthreads();
  for (int e = beg + t; e < end; e += 256) {
    int2 sc = bucket_arr[e];
    unsigned idx = (unsigned)(sc.y - lo);
    if (idx < NPB) {
      int pos = atomicAdd(&curs[idx], 1);
      csr[pos] = sc.x;
    }
  }
}

// W [K][N] f32 row-major -> Wt [N][K] f16 (transposed, for B-fragment loads)
__global__ void cvtT(const float* __restrict__ W, f16* __restrict__ Wt, int K, int N) {
  int i = blockIdx.x * 256 + threadIdx.x;
  if (i < K * N) {
    int k = i / N, n = i % N;
    Wt[(size_t)n * K + k] = (f16)W[i];
  }
}

// C = A @ B, optional epilogue *dinv[row] (dinv may be null), out f16.
// block tile 128 x NC, BK=64; mfma_f32_16x16x32_f16. LDS rows +8 halves pad.
template <int K, int NC, bool AHALF>
__global__ __launch_bounds__(256) void gemm_mfma(const void* __restrict__ Ain,
                                                 const f16* __restrict__ Bt,
                                                 const float* __restrict__ dinv,
                                                 f16* __restrict__ outp, int M) {
  constexpr int BM = 128, BK = 64, LDR = BK + 8;
  constexpr int NF = NC / 16;
  __shared__ f16 als[BM][LDR];
  __shared__ f16 bls[NC][LDR];
  const int t = threadIdx.x;
  const int lane = t & 63, w = t >> 6;
  const int r0 = blockIdx.x * BM;

  f32x4 acc[2][NF];
#pragma unroll
  for (int fr = 0; fr < 2; ++fr)
#pragma unroll
    for (int fc = 0; fc < NF; ++fc) acc[fr][fc] = (f32x4){0.f, 0.f, 0.f, 0.f};

  for (int kt = 0; kt < K; kt += BK) {
    if constexpr (AHALF) {
      const f16* Ag = (const f16*)Ain;
#pragma unroll
      for (int i0 = 0; i0 < 4; ++i0) {
        int i = t + i0 * 256;
        int row = i >> 3, ko = i & 7;
        int gr = min(r0 + row, M - 1);
        f16x8 v = *(const f16x8*)(Ag + (size_t)gr * K + kt + ko * 8);
        *(f16x4*)&als[row][ko * 8] = __builtin_shufflevector(v, v, 0, 1, 2, 3);
        *(f16x4*)&als[row][ko * 8 + 4] = __builtin_shufflevector(v, v, 4, 5, 6, 7);
      }
    } else {
      const float* Ag = (const float*)Ain;
#pragma unroll
      for (int i0 = 0; i0 < 8; ++i0) {
        int i = t + i0 * 256;
        int row = i >> 4, kq = i & 15;
        int gr = min(r0 + row, M - 1);
        float4 v = *(const float4*)(Ag + (size_t)gr * K + kt + kq * 4);
        f16x4 h = {(f16)v.x, (f16)v.y, (f16)v.z, (f16)v.w};
        *(f16x4*)&als[row][kq * 4] = h;
      }
    }
#pragma unroll
    for (int i0 = 0; i0 < NC / 32; ++i0) {
      int i = t + i0 * 256;
      int n = i >> 3, ko = i & 7;
      f16x8 v = *(const f16x8*)(Bt + (size_t)n * K + kt + ko * 8);
      *(f16x4*)&bls[n][ko * 8] = __builtin_shufflevector(v, v, 0, 1, 2, 3);
      *(f16x4*)&bls[n][ko * 8 + 4] = __builtin_shufflevector(v, v, 4, 5, 6, 7);
    }
    __syncthreads();
#pragma unroll
    for (int ks = 0; ks < 2; ++ks) {
      int kb = ks * 32 + ((lane >> 4) << 3);
      f16x8 a[2];
#pragma unroll
      for (int fr = 0; fr < 2; ++fr) {
        f16x4 lo = *(const f16x4*)&als[w * 32 + fr * 16 + (lane & 15)][kb];
        f16x4 hi = *(const f16x4*)&als[w * 32 + fr * 16 + (lane & 15)][kb + 4];
        a[fr] = __builtin_shufflevector(lo, hi, 0, 1, 2, 3, 4, 5, 6, 7);
      }
#pragma unroll
      for (int fc = 0; fc < NF; ++fc) {
        f16x4 lo = *(const f16x4*)&bls[fc * 16 + (lane & 15)][kb];
        f16x4 hi = *(const f16x4*)&bls[fc * 16 + (lane & 15)][kb + 4];
        f16x8 b = __builtin_shufflevector(lo, hi, 0, 1, 2, 3, 4, 5, 6, 7);
#pragma unroll
        for (int fr = 0; fr < 2; ++fr)
          acc[fr][fc] =
              __builtin_amdgcn_mfma_f32_16x16x32_f16(a[fr], b, acc[fr][fc], 0, 0, 0);
      }
    }
    __syncthreads();
  }
#pragma unroll
  for (int fr = 0; fr < 2; ++fr) {
#pragma unroll
    for (int reg = 0; reg < 4; ++reg) {
      int row = r0 + w * 32 + fr * 16 + ((lane >> 4) << 2) + reg;
      if (row < M) {
        float sc = dinv ? dinv[row] : 1.0f;
#pragma unroll
        for (int fc = 0; fc < NF; ++fc)
          outp[(size_t)row * NC + fc * 16 + (lane & 15)] = (f16)(acc[fr][fc][reg] * sc);
      }
    }
  }
}

// F=128 gather, wave per node. h1 is UNSCALED: apply dinv[src] per gathered
// row (wave-uniform broadcast from 400KB L2-resident table).
__global__ __launch_bounds__(256) void aggregate1_f16(
    const f16* __restrict__ hs, const int* __restrict__ offs,
    const int* __restrict__ csr, const float* __restrict__ dinv,
    const float* __restrict__ bias, f16* __restrict__ out, int N) {
  int node = blockIdx.x * 4 + (threadIdx.x >> 6);
  if (node >= N) return;
  int lane = threadIdx.x & 63;
  int beg = __builtin_amdgcn_readfirstlane(offs[node]);
  int end = __builtin_amdgcn_readfirstlane(offs[node + 1]);
  float scale = dinv[node];
  f16x2 sv = *(const f16x2*)(hs + (size_t)node * 128 + lane * 2);
  float ax = scale * (float)sv[0], ay = scale * (float)sv[1];
  for (int j0 = beg; j0 < end; j0 += 64) {
    int cnt = min(64, end - j0);
    int myidx = 0;
    if (lane < cnt) myidx = csr[j0 + lane];
    int k = 0;
    for (; k + 8 <= cnt; k += 8) {
      f16x2 v[8];
      float d[8];
#pragma unroll
      for (int u = 0; u < 8; ++u) {
        unsigned r = min((unsigned)__shfl(myidx, k + u), (unsigned)(N - 1));
        v[u] = *(const f16x2*)(hs + (size_t)r * 128 + lane * 2);
        d[u] = dinv[r];
      }
#pragma unroll
      for (int u = 0; u < 8; ++u) {
        ax = fmaf(d[u], (float)v[u][0], ax);
        ay = fmaf(d[u], (float)v[u][1], ay);
      }
    }
    for (; k < cnt; ++k) {
      unsigned r = min((unsigned)__shfl(myidx, k), (unsigned)(N - 1));
      f16x2 v = *(const f16x2*)(hs + (size_t)r * 128 + lane * 2);
      float d = dinv[r];
      ax = fmaf(d, (float)v[0], ax);
      ay = fmaf(d, (float)v[1], ay);
    }
  }
  float2 b = *(const float2*)(bias + lane * 2);
  float ox = fmaxf(fmaf(scale, ax, b.x), 0.f);
  float oy = fmaxf(fmaf(scale, ay, b.y), 0.f);
  f16x2 o = {(f16)ox, (f16)oy};
  *(f16x2*)(out + (size_t)node * 128 + lane * 2) = o;
}

// F=64 gather, half-wave per node; h2s pre-scaled (gemm2 epilogue); f32 out.
__global__ __launch_bounds__(256) void aggregate2_f16(
    const f16* __restrict__ hs, const int* __restrict__ offs,
    const int* __restrict__ csr, const float* __restrict__ dinv,
    const float* __restrict__ bias, float* __restrict__ out, int N) {
  int node = blockIdx.x * 8 + (threadIdx.x >> 5);
  if (node >= N) return;
  int sl = threadIdx.x & 31;
  int beg = offs[node], end = offs[node + 1];
  float scale = dinv[node];
  f16x2 sv = *(const f16x2*)(hs + (size_t)node * 64 + sl * 2);
  float ax = (float)sv[0], ay = (float)sv[1];
  for (int j0 = beg; j0 < end; j0 += 32) {
    int cnt = min(32, end - j0);
    int myidx = 0;
    if (sl < cnt) myidx = csr[j0 + sl];
    int k = 0;
    for (; k + 8 <= cnt; k += 8) {
      f16x2 v[8];
#pragma unroll
      for (int u = 0; u < 8; ++u) {
        unsigned r = min((unsigned)__shfl(myidx, k + u, 32), (unsigned)(N - 1));
        v[u] = *(const f16x2*)(hs + (size_t)r * 64 + sl * 2);
      }
#pragma unroll
      for (int u = 0; u < 8; ++u) {
        ax += (float)v[u][0];
        ay += (float)v[u][1];
      }
    }
    for (; k < cnt; ++k) {
      unsigned r = min((unsigned)__shfl(myidx, k, 32), (unsigned)(N - 1));
      f16x2 v = *(const f16x2*)(hs + (size_t)r * 64 + sl * 2);
      ax += (float)v[0];
      ay += (float)v[1];
    }
  }
  float2 b = *(const float2*)(bias + sl * 2);
  float2 o = {fmaf(scale, ax, b.x), fmaf(scale, ay, b.y)};
  *(float2*)(out + (size_t)node * 64 + sl * 2) = o;
}

extern "C" void kernel_launch(void* const* d_in, const int* in_sizes, int n_in,
                              void* d_out, int out_size, void* d_ws, size_t ws_size,
                              hipStream_t stream) {
  const float* x = (const float*)d_in[0];
  const int* ei = (const int*)d_in[1];
  const float* W1 = (const float*)d_in[2];
  const float* b1 = (const float*)d_in[3];
  const float* W2 = (const float*)d_in[4];
  const float* b2 = (const float*)d_in[5];
  float* out = (float*)d_out;

  const int IN = 256, HID = 128, OUT = 64;
  int N = in_sizes[0] / IN;   // 100000
  int E = in_sizes[1] / 2;    // 1600000
  int NB = (N + NPB - 1) / NPB;      // 196 buckets
  int EPB = (E + NBLK1 - 1) / NBLK1; // edges per pass1/2 block

  char* ws = (char*)d_ws;
  size_t off = 0;
  auto alloc = [&](size_t bytes) -> void* {
    void* p = ws + off;
    off += (bytes + 255) & ~(size_t)255;
    return p;
  };
  int* cntmat = (int*)alloc((size_t)NBLK1 * NB * 4);
  int* basemat = (int*)alloc((size_t)NB * NBLK1 * 4);
  int* bsums2 = (int*)alloc(1024 * 4);
  int2* bucket_arr = (int2*)alloc((size_t)E * 8);
  int* offs = (int*)alloc(((size_t)N + 1) * 4);
  float* dinv = (float*)alloc((size_t)N * 4);
  int* csr = (int*)alloc((size_t)E * 4);
  f16* Wt1 = (f16*)alloc((size_t)IN * HID * 2);
  f16* Wt2 = (f16*)alloc((size_t)HID * OUT * 2);
  f16* h1s = (f16*)alloc((size_t)N * HID * 2);
  f16* a1 = (f16*)alloc((size_t)N * HID * 2);
  f16* h2s = h1s;  // dead after aggregate1; reuse

  cvtT<<<(IN * HID + 255) / 256, 256, 0, stream>>>(W1, Wt1, IN, HID);
  cvtT<<<(HID * OUT + 255) / 256, 256, 0, stream>>>(W2, Wt2, HID, OUT);

  int gb = (N + 127) / 128;
  // gemm1 first (independent of graph build); raw h1 (dinv applied in agg1)
  gemm_mfma<256, 128, false><<<gb, 256, 0, stream>>>(x, Wt1, nullptr, h1s, N);

  pass1_count<<<NBLK1, 256, 0, stream>>>(ei, E, cntmat, N, NB, EPB);
  scan_cntmat<<<NB, 256, 0, stream>>>(cntmat, basemat, bsums2, NB);
  scan_bsums<<<1, 256, 0, stream>>>(bsums2, NB);
  pass2_scatter<<<NBLK1, 256, 0, stream>>>(ei, E, basemat, bsums2, bucket_arr, N, NB,
                                           EPB);
  pass3_build<<<NB, 256, 0, stream>>>(bucket_arr, basemat, bsums2, offs, dinv, csr, E,
                                      N, NB);

  aggregate1_f16<<<(N + 3) / 4, 256, 0, stream>>>(h1s, offs, csr, dinv, b1, a1, N);
  gemm_mfma<128, 64, true><<<gb, 256, 0, stream>>>(a1, Wt2, dinv, h2s, N);
  aggregate2_f16<<<(N + 7) / 8, 256, 0, stream>>>(h2s, offs, csr, dinv, b2, out, N);
}